// Round 3
// baseline (92.936 us; speedup 1.0000x reference)
//
#include <hip/hip_runtime.h>

// EdgeCondGCNNTF: B=2,T=32,N=64,FIN=64,FOUT=64,EDIM=16.
// Factorized: agg = H_b @ Z[b,t],  Z[b,t,j,e,:] = xn[b,t,j,:] @ W2_e,
// rank-1 eb2 term via column-sum closed form, plus node_lin GEMM.
// v6: ONE kernel (removes the precomp launch + inter-kernel drain).
//     - H (only cross-block product) computed distributed, 2 gelus/thread,
//       overlapped with x-load latency; published via hand-rolled
//       device-scope grid barrier (split arrive/wait: arrive during the
//       idle stats step, wait hidden behind phase-1 round 0).
//     - W2t/NWt: per-block o-quarter transposed into LDS with VECTOR
//       global reads (v4's sin was scalar stride-64 loads) -> no global
//       round-trip, no barrier dependency.
//     - zt 8-deep (2 GEMM rounds, 3 GEMM barriers) + union with xraw:
//       LDS ~70KB -> 2 blocks/CU capacity (residency insurance for the
//       256-block barrier; normally 1/CU).

#define LSTR 72  // LDS f16 row stride: 144B (16B-aligned rows for b128 reads)
#define XSTR 68  // LDS f32 row stride for raw x

typedef unsigned short u16;
typedef _Float16 f16;
typedef _Float16 f16x8 __attribute__((ext_vector_type(8)));
typedef _Float16 f16x4 __attribute__((ext_vector_type(4)));
typedef float f32x4 __attribute__((ext_vector_type(4)));

__device__ unsigned g_bar_cnt = 0;    // module-persistent (NOT in poisoned ws)
__device__ unsigned g_bar_sense = 0;  // monotonically increasing across launches

__device__ __forceinline__ float bf2f(u16 u) {
    union { unsigned int i; float f; } c; c.i = ((unsigned int)u) << 16; return c.f;
}
__device__ __forceinline__ u16 f2bf(float f) {
    union { float f; unsigned int i; } c; c.f = f;
    unsigned int r = c.i + 0x7FFFu + ((c.i >> 16) & 1u);
    return (u16)(r >> 16);
}
__device__ __forceinline__ float gelu_exact(float v) {
    return 0.5f * v * (1.0f + erff(v * 0.70710678118654752440f));
}
__device__ __forceinline__ float loadf(const void* p, int i, bool bf) {
    return bf ? bf2f(((const u16*)p)[i]) : ((const float*)p)[i];
}
// Sniff x's storage dtype (bf16 vs fp32). Even-index u16s: bf16 -> sane exponents.
__device__ __forceinline__ int detect_bf16(const void* xp) {
    const u16* u = (const u16*)xp;
    int sane = 0;
    #pragma unroll
    for (int k = 0; k < 64; ++k) {
        int e = (u[k * 2] >> 7) & 0xFF;
        sane += (e >= 100 && e <= 150);
    }
    return sane >= 40;
}

// ---- Single kernel: 256 blocks = (b,t) x o-quarter, 256 threads (4 waves).
__global__ __launch_bounds__(256) void fused_all(
    const void* __restrict__ x, const void* __restrict__ adj,
    const void* __restrict__ ew1, const void* __restrict__ eb1,
    const void* __restrict__ ew2, const void* __restrict__ eb2,
    const void* __restrict__ nw, const void* __restrict__ nb,
    const void* __restrict__ gw, const void* __restrict__ gb,
    const void* __restrict__ gms, f16* __restrict__ H,
    void* __restrict__ out)
{
    __shared__ union {                       // xraw dead before zt first use
        float xraw[64 * XSTR];               // 17408 B
        f16 zt[8 * 16 * LSTR];               // 18432 B  (8-deep Z, row = el*16+o_l, col = j)
    } uXZ;
    __shared__ f16 xn_lds[64 * LSTR];        //  9216 B
    __shared__ f16 w2s[(16 * 16 + 16) * LSTR]; // 39168 B: [e][o_l][f], rows 256+ = nw-quarter
    __shared__ float red1[256];
    __shared__ float red2[256];
    __shared__ float af[64], cf[64], Sv[64], t2o[64];
    __shared__ unsigned s_sense;

    const int tid  = threadIdx.x;
    const int blk  = blockIdx.x;        // 0..255
    const int bt   = blk >> 2;          // 0..63
    const int quar = blk & 3;           // o-quarter
    const int b    = bt >> 5;
    const int lane = tid & 63;
    const int wave = tid >> 6;          // 4 waves; wave = node row-tile
    const int ln   = lane & 15;
    const int q    = lane >> 4;
    const int row  = tid >> 2;          // staging: 64 rows, 4 threads/row
    const int colb = (tid & 3) << 4;    // 0,16,32,48

    const bool bf = detect_bf16(x) != 0;
    float* xraw = uXZ.xraw;
    f16*   zt   = uXZ.zt;

    // ---- (A) issue x[b,t] loads into registers first (longest latency)
    uint4 xb0, xb1; float4 xf[4];
    {
        int base = (bt << 12) + (row << 6) + colb;
        if (bf) {
            const uint4* src = (const uint4*)((const u16*)x + base);
            xb0 = src[0]; xb1 = src[1];
        } else {
            const float4* src = (const float4*)((const float*)x + base);
            #pragma unroll
            for (int k = 0; k < 4; ++k) xf[k] = src[k];
        }
    }

    // ---- (B) distributed H precomp: 2 items/thread, stores to ws.
    //      idx = blk*512 + it*256 + tid covers exactly 0..131071.
    #pragma unroll
    for (int it = 0; it < 2; ++it) {
        int idx = (blk << 9) + (it << 8) + tid;
        int hb = idx >> 16, rem = idx & 65535, e = rem >> 12, ij = rem & 4095;
        float a = loadf(adj, (hb << 12) + ij, bf);
        float v = a * loadf(ew1, e, bf) + loadf(eb1, e, bf);
        H[idx] = (f16)gelu_exact(v);
    }

    // ---- (C) this block's o-quarter of ew2 / nw, transposed into LDS.
    //      VECTOR global reads (16B/8B per load), scalar LDS writes.
    if (bf) {
        const u16* e2 = (const u16*)ew2;
        int rv2 = tid >> 1, p2 = tid & 1, f = rv2 & 63;
        #pragma unroll
        for (int it = 0; it < 8; ++it) {
            int rowi = rv2 + it * 128;             // (e,f) row index
            int e = rowi >> 6;
            uint4 v = *(const uint4*)(e2 + (rowi << 6) + (quar << 4) + (p2 << 3));
            const u16* pv = (const u16*)&v;
            #pragma unroll
            for (int k = 0; k < 8; ++k)
                w2s[((e << 4) + (p2 << 3) + k) * LSTR + f] = (f16)bf2f(pv[k]);
        }
        const u16* nwb = (const u16*)nw;
        int fr = tid >> 2, p = tid & 3;
        uint2 v = *(const uint2*)(nwb + (fr << 6) + (quar << 4) + (p << 2));
        const u16* pv = (const u16*)&v;
        #pragma unroll
        for (int k = 0; k < 4; ++k)
            w2s[(256 + (p << 2) + k) * LSTR + fr] = (f16)bf2f(pv[k]);
    } else {
        const float* e2 = (const float*)ew2;
        int rv = tid >> 2, p = tid & 3;            // rv = f, p = o-sub
        #pragma unroll
        for (int eo = 0; eo < 16; ++eo) {
            float4 v = *(const float4*)(e2 + (eo << 12) + (rv << 6) + (quar << 4) + (p << 2));
            w2s[((eo << 4) + (p << 2) + 0) * LSTR + rv] = (f16)v.x;
            w2s[((eo << 4) + (p << 2) + 1) * LSTR + rv] = (f16)v.y;
            w2s[((eo << 4) + (p << 2) + 2) * LSTR + rv] = (f16)v.z;
            w2s[((eo << 4) + (p << 2) + 3) * LSTR + rv] = (f16)v.w;
        }
        const float* nwf = (const float*)nw;
        float4 v = *(const float4*)(nwf + (rv << 6) + (quar << 4) + (p << 2));
        w2s[(256 + (p << 2) + 0) * LSTR + rv] = (f16)v.x;
        w2s[(256 + (p << 2) + 1) * LSTR + rv] = (f16)v.y;
        w2s[(256 + (p << 2) + 2) * LSTR + rv] = (f16)v.z;
        w2s[(256 + (p << 2) + 3) * LSTR + rv] = (f16)v.w;
    }

    // ---- (D) x registers -> xraw LDS
    if (bf) {
        const u16* p0 = (const u16*)&xb0;
        const u16* p1 = (const u16*)&xb1;
        #pragma unroll
        for (int k = 0; k < 8; ++k) {
            xraw[row * XSTR + colb + k]     = bf2f(p0[k]);
            xraw[row * XSTR + colb + 8 + k] = bf2f(p1[k]);
        }
    } else {
        #pragma unroll
        for (int k = 0; k < 4; ++k) {
            xraw[row * XSTR + colb + 4 * k]     = xf[k].x;
            xraw[row * XSTR + colb + 4 * k + 1] = xf[k].y;
            xraw[row * XSTR + colb + 4 * k + 2] = xf[k].z;
            xraw[row * XSTR + colb + 4 * k + 3] = xf[k].w;
        }
    }
    __syncthreads();                                   // (1) also drains H stores
    // per-feature mean / E[x^2] over the 64 nodes (column reduction, 4 partials)
    {
        int f = tid & 63, part = tid >> 6;
        float s1 = 0.f, s2 = 0.f;
        #pragma unroll
        for (int r = 0; r < 16; ++r) {
            float v = xraw[(part * 16 + r) * XSTR + f];
            s1 += v; s2 += v * v;
        }
        red1[part * 64 + f] = s1; red2[part * 64 + f] = s2;
    }
    __syncthreads();                                   // (2)
    if (tid < 64) {
        float s1 = red1[tid] + red1[64 + tid] + red1[128 + tid] + red1[192 + tid];
        float s2 = red2[tid] + red2[64 + tid] + red2[128 + tid] + red2[192 + tid];
        float mean = s1 * 0.015625f;
        float var  = s2 * 0.015625f - mean * mean;   // ddof=0
        float inv  = rsqrtf(var + 1e-5f);
        float gwf = loadf(gw, tid, bf), gbf = loadf(gb, tid, bf), g = loadf(gms, 0, bf);
        float a = inv * gwf;
        af[tid] = a;
        cf[tid] = gbf - mean * g * a;
        // S[f] = sum_j xn[j,f] = 64*(mean*(1-gms)*inv*gw + gb)  (closed form)
        Sv[tid] = 64.f * (mean * (1.f - g) * a + gbf);
    } else if (tid == 64) {
        // ---- grid-barrier ARRIVE (idle thread during stats). Block's H
        //      stores completed at (1); block-scope barrier + agent release
        //      fence publishes them device-wide.
        unsigned ms = __hip_atomic_load(&g_bar_sense, __ATOMIC_RELAXED,
                                        __HIP_MEMORY_SCOPE_AGENT);
        s_sense = ms;
        __threadfence();   // agent-scope release: L2 writeback of H
        unsigned prev = __hip_atomic_fetch_add(&g_bar_cnt, 1u, __ATOMIC_ACQ_REL,
                                               __HIP_MEMORY_SCOPE_AGENT);
        if (prev == gridDim.x - 1) {
            __hip_atomic_store(&g_bar_cnt, 0u, __ATOMIC_RELAXED,
                               __HIP_MEMORY_SCOPE_AGENT);
            __hip_atomic_fetch_add(&g_bar_sense, 1u, __ATOMIC_RELEASE,
                                   __HIP_MEMORY_SCOPE_AGENT);
        }
    }
    __syncthreads();                                   // (3)
    // normalize: xraw -> xn_lds as f16
    {
        #pragma unroll
        for (int k = 0; k < 16; ++k) {
            int col = colb + k;
            xn_lds[row * LSTR + col] = (f16)(xraw[row * XSTR + col] * af[col] + cf[col]);
        }
    }
    // t2[o] = sum_f S[f]*eb2[f,o] partials (the eb2 part of edge_w)
    {
        int o = tid & 63, part = tid >> 6;
        float s = 0.f;
        #pragma unroll
        for (int r = 0; r < 16; ++r) {
            int f = part * 16 + r;
            s += Sv[f] * loadf(eb2, (f << 6) + o, bf);
        }
        red1[part * 64 + o] = s;
    }
    __syncthreads();                                   // (4) xraw dead after here
    if (tid < 64)
        t2o[tid] = red1[tid] + red1[64 + tid] + red1[128 + tid] + red1[192 + tid]
                 + loadf(nb, tid, bf);

    // hoisted xn A-fragments (this wave's node row-tile, full K=f)
    f16x8 xa0 = *(const f16x8*)&xn_lds[(wave * 16 + ln) * LSTR + q * 8];
    f16x8 xa1 = *(const f16x8*)&xn_lds[(wave * 16 + ln) * LSTR + 32 + q * 8];

    f32x4 acc0 = {0.f,0.f,0.f,0.f}, acc1 = {0.f,0.f,0.f,0.f};
    f32x4 acc2 = {0.f,0.f,0.f,0.f}, acc3 = {0.f,0.f,0.f,0.f};
    const f16* hbase = H + (b << 16) + ((wave * 16 + ln) << 6) + q * 8;

    #pragma unroll
    for (int r = 0; r < 2; ++r) {
        // ---- phase 1 (round r): Z_e = xn @ W2_e, e in [r*8, r*8+8).
        //      B-frags from w2s LDS; independent of the grid barrier.
        #pragma unroll
        for (int el = 0; el < 8; ++el) {
            int e = r * 8 + el;
            const f16* wrow = &w2s[((e << 4) + ln) * LSTR];
            f16x8 b0 = *(const f16x8*)(wrow + q * 8);
            f16x8 b1 = *(const f16x8*)(wrow + 32 + q * 8);
            f32x4 z = {0.f, 0.f, 0.f, 0.f};
            z = __builtin_amdgcn_mfma_f32_16x16x32_f16(xa0, b0, z, 0, 0, 0);
            z = __builtin_amdgcn_mfma_f32_16x16x32_f16(xa1, b1, z, 0, 0, 0);
            // C/D: row(j-in-tile)=q*4+rr, col(o_local)=ln
            f16x4 p;
            #pragma unroll
            for (int rr = 0; rr < 4; ++rr) p[rr] = (f16)z[rr];
            *(f16x4*)&zt[((el << 4) + ln) * LSTR + wave * 16 + q * 4] = p;
        }
        if (r == 0) {
            // ---- grid-barrier WAIT, hidden behind phase-1 round 0.
            if (tid == 0) {
                unsigned ms = s_sense;
                unsigned spins = 0;
                while (__hip_atomic_load(&g_bar_sense, __ATOMIC_ACQUIRE,
                                         __HIP_MEMORY_SCOPE_AGENT) == ms) {
                    __builtin_amdgcn_s_sleep(2);
                    if (++spins > (1u << 26)) break;   // anti-hang valve (~seconds)
                }
            }
        }
        __syncthreads();                               // (5)/(7): zt ready (+H visible at r=0)
        // ---- phase 2 (round r): acc += H_be @ Z_e. A-frags from global H.
        #pragma unroll
        for (int kk = 0; kk < 16; ++kk) {
            int el = kk >> 1, jh = kk & 1, e = r * 8 + el;
            f16x8 ha = *(const f16x8*)(hbase + (e << 12) + jh * 32);
            f16x8 zb = *(const f16x8*)&zt[((el << 4) + ln) * LSTR + jh * 32 + q * 8];
            switch (kk & 3) {
                case 0: acc0 = __builtin_amdgcn_mfma_f32_16x16x32_f16(ha, zb, acc0, 0, 0, 0); break;
                case 1: acc1 = __builtin_amdgcn_mfma_f32_16x16x32_f16(ha, zb, acc1, 0, 0, 0); break;
                case 2: acc2 = __builtin_amdgcn_mfma_f32_16x16x32_f16(ha, zb, acc2, 0, 0, 0); break;
                default: acc3 = __builtin_amdgcn_mfma_f32_16x16x32_f16(ha, zb, acc3, 0, 0, 0); break;
            }
        }
        if (r == 0) __syncthreads();                   // (6): zt reuse by round 1
    }
    // node_lin: acc += xn @ nw (B-frags from w2s rows 256+, this o-quarter)
    {
        const f16* nrow = &w2s[(256 + ln) * LSTR];
        f16x8 b0 = *(const f16x8*)(nrow + q * 8);
        f16x8 b1 = *(const f16x8*)(nrow + 32 + q * 8);
        acc0 = __builtin_amdgcn_mfma_f32_16x16x32_f16(xa0, b0, acc0, 0, 0, 0);
        acc1 = __builtin_amdgcn_mfma_f32_16x16x32_f16(xa1, b1, acc1, 0, 0, 0);
    }
    // epilogue: merge chains, + t2[o] (nb folded in), exact GELU, store per mode
    {
        const int o = (quar << 4) + ln;
        const float add = t2o[o];
        if (bf) {
            u16* ob = (u16*)out + (bt << 12);
            #pragma unroll
            for (int rr = 0; rr < 4; ++rr) {
                int i = wave * 16 + q * 4 + rr;
                float v = acc0[rr] + acc1[rr] + acc2[rr] + acc3[rr] + add;
                ob[(i << 6) + o] = f2bf(gelu_exact(v));
            }
        } else {
            float* ob = (float*)out + (bt << 12);
            #pragma unroll
            for (int rr = 0; rr < 4; ++rr) {
                int i = wave * 16 + q * 4 + rr;
                float v = acc0[rr] + acc1[rr] + acc2[rr] + acc3[rr] + add;
                ob[(i << 6) + o] = gelu_exact(v);
            }
        }
    }
}

extern "C" void kernel_launch(void* const* d_in, const int* in_sizes, int n_in,
                              void* d_out, int out_size, void* d_ws, size_t ws_size,
                              hipStream_t stream) {
    const void* x   = d_in[0];
    const void* adj = d_in[1];
    const void* ew1 = d_in[2];
    const void* eb1 = d_in[3];
    const void* ew2 = d_in[4];
    const void* eb2 = d_in[5];
    const void* nw  = d_in[6];
    const void* nb  = d_in[7];
    const void* gw  = d_in[8];
    const void* gb  = d_in[9];
    const void* gms = d_in[10];

    f16* H = (f16*)d_ws;   // 131072 f16 = 256 KB of ws

    fused_all<<<256, 256, 0, stream>>>(x, adj, ew1, eb1, ew2, eb2, nw, nb,
                                       gw, gb, gms, H, d_out);
}

// Round 4
// 87.566 us; speedup vs baseline: 1.0613x; 1.0613x over previous
//
#include <hip/hip_runtime.h>

// EdgeCondGCNNTF: B=2,T=32,N=64,FIN=64,FOUT=64,EDIM=16.
// Factorized: agg = H_b @ Z[b,t],  Z[b,t,j,e,:] = xn[b,t,j,:] @ W2_e,
// rank-1 eb2 term via column-sum closed form, plus node_lin GEMM.
// v7: two launches (v6 proved grid-barrier skew > launch cost), but the
//     ENTIRE norm/stats/t2o prologue moves into precomp as 64 dedicated
//     blocks running concurrently with the H/W2t/NWt blocks (which only
//     occupied ~0.65 items/thread of an otherwise idle device).
//     fused_main collapses to: frag loads from ws -> phase1 -> ONE sync
//     -> phase2 -> epilogue. Barriers 5 -> 1, no LDS staging, no detect
//     loop (dtype flag precomputed in ws).

#define LSTR 72  // LDS f16 row stride: 144B (16B-aligned rows for b128 reads)
#define XSTR 68  // LDS f32 row stride for raw x

typedef unsigned short u16;
typedef _Float16 f16;
typedef _Float16 f16x8 __attribute__((ext_vector_type(8)));
typedef _Float16 f16x4 __attribute__((ext_vector_type(4)));
typedef float f32x4 __attribute__((ext_vector_type(4)));

__device__ __forceinline__ float bf2f(u16 u) {
    union { unsigned int i; float f; } c; c.i = ((unsigned int)u) << 16; return c.f;
}
__device__ __forceinline__ u16 f2bf(float f) {
    union { float f; unsigned int i; } c; c.f = f;
    unsigned int r = c.i + 0x7FFFu + ((c.i >> 16) & 1u);
    return (u16)(r >> 16);
}
__device__ __forceinline__ float gelu_exact(float v) {
    return 0.5f * v * (1.0f + erff(v * 0.70710678118654752440f));
}
__device__ __forceinline__ float loadf(const void* p, int i, bool bf) {
    return bf ? bf2f(((const u16*)p)[i]) : ((const float*)p)[i];
}
// Sniff x's storage dtype (bf16 vs fp32). Even-index u16s: bf16 -> sane exponents.
__device__ __forceinline__ int detect_bf16(const void* xp) {
    const u16* u = (const u16*)xp;
    int sane = 0;
    #pragma unroll
    for (int k = 0; k < 64; ++k) {
        int e = (u[k * 2] >> 7) & 0xFF;
        sane += (e >= 100 && e <= 150);
    }
    return sane >= 40;
}

// ws layout (f16 units unless noted):
//   H    [0, 131072)                 : H[b][e][i][j]
//   W2t  [131072, 196608)            : W2t[e][o][f]
//   NWt  [196608, 200704)            : NWt[o][f]
//   xn   [200704, 462848)            : xn[bt][j][f]   (16B-aligned: 200704*2 % 16 == 0)
//   t2o  f32 @ f16-idx 462848        : t2o[bt][o]  (4096 floats)
//   flag u32 @ f16-idx 471040        : bf16 dtype flag

// ---- Kernel A: 512 blocks.
//   blocks 0..63   : norm role, bt = blk. x -> stats -> xn(ws f16), t2o(ws f32), flag.
//   blocks 64..511 : 2 items/thread over H (gelu(adj*ew1+eb1)), W2t, NWt transposes.
__global__ __launch_bounds__(256) void precomp(
    const void* __restrict__ x, const void* __restrict__ adj,
    const void* __restrict__ ew1, const void* __restrict__ eb1,
    const void* __restrict__ ew2, const void* __restrict__ eb2,
    const void* __restrict__ nw, const void* __restrict__ nb,
    const void* __restrict__ gw, const void* __restrict__ gb,
    const void* __restrict__ gms, f16* __restrict__ ws)
{
    __shared__ float xraw[64 * XSTR];
    __shared__ float red1[256];
    __shared__ float red2[256];
    __shared__ float af[64], cf[64], Sv[64];

    const int blk = blockIdx.x, tid = threadIdx.x;
    const bool bf = detect_bf16(x) != 0;

    if (blk >= 64) {
        // ---- compute role: H / W2t / NWt, 2 items/thread
        f16* H   = ws;
        f16* W2t = ws + 131072;
        f16* NWt = ws + 196608;
        #pragma unroll
        for (int it = 0; it < 2; ++it) {
            int idx = ((blk - 64) << 9) + (it << 8) + tid;
            if (idx < 131072) {                       // B*EDIM*N*N
                int b = idx >> 16, rem = idx & 65535, e = rem >> 12, ij = rem & 4095;
                float a = loadf(adj, (b << 12) + ij, bf);
                float v = a * loadf(ew1, e, bf) + loadf(eb1, e, bf);
                H[idx] = (f16)gelu_exact(v);
            } else if (idx < 196608) {                // EDIM*FOUT*FIN
                int k = idx - 131072, e = k >> 12, of = k & 4095, o = of >> 6, f = of & 63;
                W2t[k] = (f16)loadf(ew2, (e << 12) + (f << 6) + o, bf);
            } else if (idx < 200704) {                // FOUT*FIN
                int k = idx - 196608, o = k >> 6, f = k & 63;
                NWt[k] = (f16)loadf(nw, (f << 6) + o, bf);
            }
        }
        return;
    }

    // ---- norm role: bt = blk
    const int bt   = blk;
    const int row  = tid >> 2;          // 64 rows, 4 threads/row
    const int colb = (tid & 3) << 4;    // 0,16,32,48
    f16*   xn  = ws + 200704 + (bt << 12);
    float* t2o = (float*)(ws + 462848) + (bt << 6);

    if (blk == 0 && tid == 0) *(unsigned*)(ws + 471040) = bf ? 1u : 0u;

    // stage raw x[bt] into xraw (fp32), coalesced vector loads per mode
    {
        int base = (bt << 12) + (row << 6) + colb;
        if (bf) {
            const uint4* src = (const uint4*)((const u16*)x + base);
            uint4 v0 = src[0], v1 = src[1];
            const u16* p0 = (const u16*)&v0;
            const u16* p1 = (const u16*)&v1;
            #pragma unroll
            for (int k = 0; k < 8; ++k) {
                xraw[row * XSTR + colb + k]     = bf2f(p0[k]);
                xraw[row * XSTR + colb + 8 + k] = bf2f(p1[k]);
            }
        } else {
            const float4* src = (const float4*)((const float*)x + base);
            #pragma unroll
            for (int k = 0; k < 4; ++k) {
                float4 v = src[k];
                xraw[row * XSTR + colb + 4 * k]     = v.x;
                xraw[row * XSTR + colb + 4 * k + 1] = v.y;
                xraw[row * XSTR + colb + 4 * k + 2] = v.z;
                xraw[row * XSTR + colb + 4 * k + 3] = v.w;
            }
        }
    }
    __syncthreads();
    // per-feature mean / E[x^2] over the 64 nodes (column reduction, 4 partials)
    {
        int f = tid & 63, part = tid >> 6;
        float s1 = 0.f, s2 = 0.f;
        #pragma unroll
        for (int r = 0; r < 16; ++r) {
            float v = xraw[(part * 16 + r) * XSTR + f];
            s1 += v; s2 += v * v;
        }
        red1[part * 64 + f] = s1; red2[part * 64 + f] = s2;
    }
    __syncthreads();
    if (tid < 64) {
        float s1 = red1[tid] + red1[64 + tid] + red1[128 + tid] + red1[192 + tid];
        float s2 = red2[tid] + red2[64 + tid] + red2[128 + tid] + red2[192 + tid];
        float mean = s1 * 0.015625f;
        float var  = s2 * 0.015625f - mean * mean;   // ddof=0
        float inv  = rsqrtf(var + 1e-5f);
        float gwf = loadf(gw, tid, bf), gbf = loadf(gb, tid, bf), g = loadf(gms, 0, bf);
        float a = inv * gwf;
        af[tid] = a;
        cf[tid] = gbf - mean * g * a;
        // S[f] = sum_j xn[j,f] = 64*(mean*(1-gms)*inv*gw + gb)  (closed form)
        Sv[tid] = 64.f * (mean * (1.f - g) * a + gbf);
    }
    __syncthreads();
    // normalize: xraw -> xn (ws, f16). 16 consecutive f16/thread = 32B, coalesced.
    {
        f16 tmp[16];
        #pragma unroll
        for (int k = 0; k < 16; ++k) {
            int col = colb + k;
            tmp[k] = (f16)(xraw[row * XSTR + col] * af[col] + cf[col]);
        }
        *(f16x8*)&xn[(row << 6) + colb]     = *(f16x8*)&tmp[0];
        *(f16x8*)&xn[(row << 6) + colb + 8] = *(f16x8*)&tmp[8];
    }
    // t2[o] = sum_f S[f]*eb2[f,o] partials (the eb2 part of edge_w)
    {
        int o = tid & 63, part = tid >> 6;
        float s = 0.f;
        #pragma unroll
        for (int r = 0; r < 16; ++r) {
            int f = part * 16 + r;
            s += Sv[f] * loadf(eb2, (f << 6) + o, bf);
        }
        red1[part * 64 + o] = s;
    }
    __syncthreads();
    if (tid < 64)
        t2o[tid] = red1[tid] + red1[64 + tid] + red1[128 + tid] + red1[192 + tid]
                 + loadf(nb, tid, bf);
}

// ---- Kernel B: 256 blocks = (b,t) x o-quarter. No staging, ONE barrier:
//      frag loads from ws -> phase1 (Z into zt) -> sync -> phase2 K=1024+64.
__global__ __launch_bounds__(256) void fused_main(
    const f16* __restrict__ ws, void* __restrict__ out)
{
    __shared__ f16 zt[16 * 16 * LSTR];   // 36864 B: row = e*16 + o_local, col = j

    const int tid  = threadIdx.x;
    const int blk  = blockIdx.x;        // 0..255
    const int bt   = blk >> 2;          // 0..63
    const int quar = blk & 3;           // o-quarter
    const int b    = bt >> 5;
    const int lane = tid & 63;
    const int wave = tid >> 6;          // 4 waves; wave = node row-tile
    const int ln   = lane & 15;
    const int q    = lane >> 4;

    const f16* H   = ws;
    const f16* W2t = ws + 131072;
    const f16* NWt = ws + 196608;
    const f16* xn  = ws + 200704 + (bt << 12);
    const float* t2o = (const float*)(ws + 462848) + (bt << 6);
    const bool bf = *(const unsigned*)(ws + 471040) != 0;

    // xn A-fragments (this wave's node row-tile, full K=f) from ws (L2-warm)
    f16x8 xa0 = *(const f16x8*)&xn[((wave * 16 + ln) << 6) + q * 8];
    f16x8 xa1 = *(const f16x8*)&xn[((wave * 16 + ln) << 6) + 32 + q * 8];

    // ---- phase 1: Z_e = xn @ W2_e for ALL 16 e (this o-quarter, 16 cols).
    //      B-frags direct from global W2t (L2-resident). No barriers inside.
    #pragma unroll
    for (int e = 0; e < 16; ++e) {
        const f16* wrow = W2t + (((e << 6) + (quar << 4) + ln) << 6);
        f16x8 b0 = *(const f16x8*)(wrow + q * 8);
        f16x8 b1 = *(const f16x8*)(wrow + 32 + q * 8);
        f32x4 z = {0.f, 0.f, 0.f, 0.f};
        z = __builtin_amdgcn_mfma_f32_16x16x32_f16(xa0, b0, z, 0, 0, 0);
        z = __builtin_amdgcn_mfma_f32_16x16x32_f16(xa1, b1, z, 0, 0, 0);
        // C/D: row(j-in-tile)=q*4+r, col(o_local)=ln -> zt[e*16+o_local][j]
        f16x4 p;
        #pragma unroll
        for (int r = 0; r < 4; ++r) p[r] = (f16)z[r];
        *(f16x4*)&zt[((e << 4) + ln) * LSTR + wave * 16 + q * 4] = p;
    }
    __syncthreads();                    // the only barrier

    // ---- phase 2: acc += Hbig @ Zbig, K = (e,j) = 1024, one chain;
    //      4 accumulator chains over kk&3 (statically unrolled).
    f32x4 acc0 = {0.f,0.f,0.f,0.f}, acc1 = {0.f,0.f,0.f,0.f};
    f32x4 acc2 = {0.f,0.f,0.f,0.f}, acc3 = {0.f,0.f,0.f,0.f};
    const f16* hbase = H + (b << 16) + ((wave * 16 + ln) << 6) + q * 8;
    #pragma unroll
    for (int kk = 0; kk < 32; ++kk) {
        const int e = kk >> 1, jh = kk & 1;
        f16x8 ha = *(const f16x8*)(hbase + (e << 12) + jh * 32);
        f16x8 zb = *(const f16x8*)&zt[((e << 4) + ln) * LSTR + jh * 32 + q * 8];
        switch (kk & 3) {
            case 0: acc0 = __builtin_amdgcn_mfma_f32_16x16x32_f16(ha, zb, acc0, 0, 0, 0); break;
            case 1: acc1 = __builtin_amdgcn_mfma_f32_16x16x32_f16(ha, zb, acc1, 0, 0, 0); break;
            case 2: acc2 = __builtin_amdgcn_mfma_f32_16x16x32_f16(ha, zb, acc2, 0, 0, 0); break;
            default: acc3 = __builtin_amdgcn_mfma_f32_16x16x32_f16(ha, zb, acc3, 0, 0, 0); break;
        }
    }
    // node_lin: acc += xn @ nw (B-frags direct from global NWt, this o-quarter)
    {
        const f16* nrow = NWt + (((quar << 4) + ln) << 6);
        f16x8 b0 = *(const f16x8*)(nrow + q * 8);
        f16x8 b1 = *(const f16x8*)(nrow + 32 + q * 8);
        acc0 = __builtin_amdgcn_mfma_f32_16x16x32_f16(xa0, b0, acc0, 0, 0, 0);
        acc1 = __builtin_amdgcn_mfma_f32_16x16x32_f16(xa1, b1, acc1, 0, 0, 0);
    }
    // epilogue: merge chains, + t2[o] (nb folded in), exact GELU, store per mode
    {
        const int o = (quar << 4) + ln;
        const float add = t2o[o];
        if (bf) {
            u16* ob = (u16*)out + (bt << 12);
            #pragma unroll
            for (int r = 0; r < 4; ++r) {
                int i = wave * 16 + q * 4 + r;
                float v = acc0[r] + acc1[r] + acc2[r] + acc3[r] + add;
                ob[(i << 6) + o] = f2bf(gelu_exact(v));
            }
        } else {
            float* ob = (float*)out + (bt << 12);
            #pragma unroll
            for (int r = 0; r < 4; ++r) {
                int i = wave * 16 + q * 4 + r;
                float v = acc0[r] + acc1[r] + acc2[r] + acc3[r] + add;
                ob[(i << 6) + o] = gelu_exact(v);
            }
        }
    }
}

extern "C" void kernel_launch(void* const* d_in, const int* in_sizes, int n_in,
                              void* d_out, int out_size, void* d_ws, size_t ws_size,
                              hipStream_t stream) {
    const void* x   = d_in[0];
    const void* adj = d_in[1];
    const void* ew1 = d_in[2];
    const void* eb1 = d_in[3];
    const void* ew2 = d_in[4];
    const void* eb2 = d_in[5];
    const void* nw  = d_in[6];
    const void* nb  = d_in[7];
    const void* gw  = d_in[8];
    const void* gb  = d_in[9];
    const void* gms = d_in[10];

    f16* ws = (f16*)d_ws;   // ~944 KB used, see layout comment

    precomp<<<512, 256, 0, stream>>>(x, adj, ew1, eb1, ew2, eb2, nw, nb,
                                     gw, gb, gms, ws);
    fused_main<<<256, 256, 0, stream>>>(ws, d_out);
}

// Round 6
// 87.557 us; speedup vs baseline: 1.0614x; 1.0001x over previous
//
#include <hip/hip_runtime.h>

// EdgeCondGCNNTF: B=2,T=32,N=64,FIN=64,FOUT=64,EDIM=16.
// Factorized: agg = H_b @ Z[b,t],  Z[b,t,j,e,:] = xn[b,t,j,:] @ W2_e,
// rank-1 eb2 term via column-sum closed form, plus node_lin GEMM.
// v9 = v7 + phase-2 de-latency via REGISTERS (v8's LDS staging overflowed:
//     H[b] is 128KB, not 64KB; 128K + 36.9K zt > 160K limit).
//     - All 32 per-lane H A-fragments (128 VGPRs) prefetched at kernel top;
//       their L2 latency hides under phase-1's 32 MFMAs + W2t traffic.
//       Phase 2 is then a pure register MFMA chain + cheap zt LDS reads.
//     - __launch_bounds__(256,1): 1 wave/SIMD (= existing occupancy) ->
//       ~512 VGPR budget, no spill at ~190 used.
//     precomp unchanged from v7.

#define LSTR 72  // LDS f16 row stride: 144B (16B-aligned rows for b128 reads)
#define XSTR 68  // LDS f32 row stride for raw x

typedef unsigned short u16;
typedef _Float16 f16;
typedef _Float16 f16x8 __attribute__((ext_vector_type(8)));
typedef _Float16 f16x4 __attribute__((ext_vector_type(4)));
typedef float f32x4 __attribute__((ext_vector_type(4)));

__device__ __forceinline__ float bf2f(u16 u) {
    union { unsigned int i; float f; } c; c.i = ((unsigned int)u) << 16; return c.f;
}
__device__ __forceinline__ u16 f2bf(float f) {
    union { float f; unsigned int i; } c; c.f = f;
    unsigned int r = c.i + 0x7FFFu + ((c.i >> 16) & 1u);
    return (u16)(r >> 16);
}
__device__ __forceinline__ float gelu_exact(float v) {
    return 0.5f * v * (1.0f + erff(v * 0.70710678118654752440f));
}
__device__ __forceinline__ float loadf(const void* p, int i, bool bf) {
    return bf ? bf2f(((const u16*)p)[i]) : ((const float*)p)[i];
}
// Sniff x's storage dtype (bf16 vs fp32). Even-index u16s: bf16 -> sane exponents.
__device__ __forceinline__ int detect_bf16(const void* xp) {
    const u16* u = (const u16*)xp;
    int sane = 0;
    #pragma unroll
    for (int k = 0; k < 64; ++k) {
        int e = (u[k * 2] >> 7) & 0xFF;
        sane += (e >= 100 && e <= 150);
    }
    return sane >= 40;
}

// ws layout (f16 units unless noted):
//   H    [0, 131072)                 : H[b][e][i][j]
//   W2t  [131072, 196608)            : W2t[e][o][f]
//   NWt  [196608, 200704)            : NWt[o][f]
//   xn   [200704, 462848)            : xn[bt][j][f]   (16B-aligned)
//   t2o  f32 @ f16-idx 462848        : t2o[bt][o]  (4096 floats)
//   flag u32 @ f16-idx 471040        : bf16 dtype flag

// ---- Kernel A: 512 blocks.
//   blocks 0..63   : norm role, bt = blk. x -> stats -> xn(ws f16), t2o(ws f32), flag.
//   blocks 64..511 : 2 items/thread over H (gelu(adj*ew1+eb1)), W2t, NWt transposes.
__global__ __launch_bounds__(256) void precomp(
    const void* __restrict__ x, const void* __restrict__ adj,
    const void* __restrict__ ew1, const void* __restrict__ eb1,
    const void* __restrict__ ew2, const void* __restrict__ eb2,
    const void* __restrict__ nw, const void* __restrict__ nb,
    const void* __restrict__ gw, const void* __restrict__ gb,
    const void* __restrict__ gms, f16* __restrict__ ws)
{
    __shared__ float xraw[64 * XSTR];
    __shared__ float red1[256];
    __shared__ float red2[256];
    __shared__ float af[64], cf[64], Sv[64];

    const int blk = blockIdx.x, tid = threadIdx.x;
    const bool bf = detect_bf16(x) != 0;

    if (blk >= 64) {
        // ---- compute role: H / W2t / NWt, 2 items/thread
        f16* H   = ws;
        f16* W2t = ws + 131072;
        f16* NWt = ws + 196608;
        #pragma unroll
        for (int it = 0; it < 2; ++it) {
            int idx = ((blk - 64) << 9) + (it << 8) + tid;
            if (idx < 131072) {                       // B*EDIM*N*N
                int b = idx >> 16, rem = idx & 65535, e = rem >> 12, ij = rem & 4095;
                float a = loadf(adj, (b << 12) + ij, bf);
                float v = a * loadf(ew1, e, bf) + loadf(eb1, e, bf);
                H[idx] = (f16)gelu_exact(v);
            } else if (idx < 196608) {                // EDIM*FOUT*FIN
                int k = idx - 131072, e = k >> 12, of = k & 4095, o = of >> 6, f = of & 63;
                W2t[k] = (f16)loadf(ew2, (e << 12) + (f << 6) + o, bf);
            } else if (idx < 200704) {                // FOUT*FIN
                int k = idx - 196608, o = k >> 6, f = k & 63;
                NWt[k] = (f16)loadf(nw, (f << 6) + o, bf);
            }
        }
        return;
    }

    // ---- norm role: bt = blk
    const int bt   = blk;
    const int row  = tid >> 2;          // 64 rows, 4 threads/row
    const int colb = (tid & 3) << 4;    // 0,16,32,48
    f16*   xn  = ws + 200704 + (bt << 12);
    float* t2o = (float*)(ws + 462848) + (bt << 6);

    if (blk == 0 && tid == 0) *(unsigned*)(ws + 471040) = bf ? 1u : 0u;

    // stage raw x[bt] into xraw (fp32), coalesced vector loads per mode
    {
        int base = (bt << 12) + (row << 6) + colb;
        if (bf) {
            const uint4* src = (const uint4*)((const u16*)x + base);
            uint4 v0 = src[0], v1 = src[1];
            const u16* p0 = (const u16*)&v0;
            const u16* p1 = (const u16*)&v1;
            #pragma unroll
            for (int k = 0; k < 8; ++k) {
                xraw[row * XSTR + colb + k]     = bf2f(p0[k]);
                xraw[row * XSTR + colb + 8 + k] = bf2f(p1[k]);
            }
        } else {
            const float4* src = (const float4*)((const float*)x + base);
            #pragma unroll
            for (int k = 0; k < 4; ++k) {
                float4 v = src[k];
                xraw[row * XSTR + colb + 4 * k]     = v.x;
                xraw[row * XSTR + colb + 4 * k + 1] = v.y;
                xraw[row * XSTR + colb + 4 * k + 2] = v.z;
                xraw[row * XSTR + colb + 4 * k + 3] = v.w;
            }
        }
    }
    __syncthreads();
    // per-feature mean / E[x^2] over the 64 nodes (column reduction, 4 partials)
    {
        int f = tid & 63, part = tid >> 6;
        float s1 = 0.f, s2 = 0.f;
        #pragma unroll
        for (int r = 0; r < 16; ++r) {
            float v = xraw[(part * 16 + r) * XSTR + f];
            s1 += v; s2 += v * v;
        }
        red1[part * 64 + f] = s1; red2[part * 64 + f] = s2;
    }
    __syncthreads();
    if (tid < 64) {
        float s1 = red1[tid] + red1[64 + tid] + red1[128 + tid] + red1[192 + tid];
        float s2 = red2[tid] + red2[64 + tid] + red2[128 + tid] + red2[192 + tid];
        float mean = s1 * 0.015625f;
        float var  = s2 * 0.015625f - mean * mean;   // ddof=0
        float inv  = rsqrtf(var + 1e-5f);
        float gwf = loadf(gw, tid, bf), gbf = loadf(gb, tid, bf), g = loadf(gms, 0, bf);
        float a = inv * gwf;
        af[tid] = a;
        cf[tid] = gbf - mean * g * a;
        // S[f] = sum_j xn[j,f] = 64*(mean*(1-gms)*inv*gw + gb)  (closed form)
        Sv[tid] = 64.f * (mean * (1.f - g) * a + gbf);
    }
    __syncthreads();
    // normalize: xraw -> xn (ws, f16). 16 consecutive f16/thread = 32B, coalesced.
    {
        f16 tmp[16];
        #pragma unroll
        for (int k = 0; k < 16; ++k) {
            int col = colb + k;
            tmp[k] = (f16)(xraw[row * XSTR + col] * af[col] + cf[col]);
        }
        *(f16x8*)&xn[(row << 6) + colb]     = *(f16x8*)&tmp[0];
        *(f16x8*)&xn[(row << 6) + colb + 8] = *(f16x8*)&tmp[8];
    }
    // t2[o] = sum_f S[f]*eb2[f,o] partials (the eb2 part of edge_w)
    {
        int o = tid & 63, part = tid >> 6;
        float s = 0.f;
        #pragma unroll
        for (int r = 0; r < 16; ++r) {
            int f = part * 16 + r;
            s += Sv[f] * loadf(eb2, (f << 6) + o, bf);
        }
        red1[part * 64 + o] = s;
    }
    __syncthreads();
    if (tid < 64)
        t2o[tid] = red1[tid] + red1[64 + tid] + red1[128 + tid] + red1[192 + tid]
                 + loadf(nb, tid, bf);
}

// ---- Kernel B: 256 blocks = (b,t) x o-quarter. One barrier.
//      All 32 H A-frags prefetched to REGISTERS at top (latency hides under
//      phase 1); phase1 (Z into zt LDS); barrier; phase2 = register-operand
//      K=1024 MFMA chain + node_lin; epilogue.
__global__ __launch_bounds__(256, 1) void fused_main(
    const f16* __restrict__ ws, void* __restrict__ out)
{
    __shared__ f16 zt[16 * 16 * LSTR];   // 36864 B: row = e*16 + o_local, col = j

    const int tid  = threadIdx.x;
    const int blk  = blockIdx.x;        // 0..255
    const int bt   = blk >> 2;          // 0..63
    const int quar = blk & 3;           // o-quarter
    const int b    = bt >> 5;
    const int lane = tid & 63;
    const int wave = tid >> 6;          // 4 waves; wave = node row-tile
    const int ln   = lane & 15;
    const int q    = lane >> 4;

    const f16* H   = ws;
    const f16* W2t = ws + 131072;
    const f16* NWt = ws + 196608;
    const f16* xn  = ws + 200704 + (bt << 12);
    const float* t2o = (const float*)(ws + 462848) + (bt << 6);

    // ---- early loads: xa frags, node_lin B-frags, t2o scalar, dtype flag
    f16x8 xa0 = *(const f16x8*)&xn[((wave * 16 + ln) << 6) + q * 8];
    f16x8 xa1 = *(const f16x8*)&xn[((wave * 16 + ln) << 6) + 32 + q * 8];
    const f16* nrow = NWt + (((quar << 4) + ln) << 6);
    f16x8 nb0 = *(const f16x8*)(nrow + q * 8);
    f16x8 nb1 = *(const f16x8*)(nrow + 32 + q * 8);
    const float add = t2o[(quar << 4) + ln];
    const bool bf = *(const unsigned*)(ws + 471040) != 0;

    // ---- prefetch ALL 32 per-lane H A-fragments into registers (128 VGPRs).
    //      kk = e*2 + jh; addr = H[b][e][wave*16+ln][jh*32 + q*8 .. +8).
    //      32 dwordx4 loads in flight; latency hides under phase-1 MFMAs.
    const f16* hbase = H + (b << 16) + ((wave * 16 + ln) << 6) + q * 8;
    f16x8 ha[32];
    #pragma unroll
    for (int kk = 0; kk < 32; ++kk) {
        const int e = kk >> 1, jh = kk & 1;
        ha[kk] = *(const f16x8*)(hbase + (e << 12) + jh * 32);
    }

    // ---- phase 1: Z_e = xn @ W2_e for ALL 16 e (this o-quarter, 16 cols).
    //      B-frags direct from global W2t (L2-resident). No barriers inside.
    #pragma unroll
    for (int e = 0; e < 16; ++e) {
        const f16* wrow = W2t + (((e << 6) + (quar << 4) + ln) << 6);
        f16x8 b0 = *(const f16x8*)(wrow + q * 8);
        f16x8 b1 = *(const f16x8*)(wrow + 32 + q * 8);
        f32x4 z = {0.f, 0.f, 0.f, 0.f};
        z = __builtin_amdgcn_mfma_f32_16x16x32_f16(xa0, b0, z, 0, 0, 0);
        z = __builtin_amdgcn_mfma_f32_16x16x32_f16(xa1, b1, z, 0, 0, 0);
        // C/D: row(j-in-tile)=q*4+r, col(o_local)=ln -> zt[e*16+o_local][j]
        f16x4 p;
        #pragma unroll
        for (int r = 0; r < 4; ++r) p[r] = (f16)z[r];
        *(f16x4*)&zt[((e << 4) + ln) * LSTR + wave * 16 + q * 4] = p;
    }
    __syncthreads();                    // the only barrier

    // ---- phase 2: acc += Hbig @ Zbig, K = (e,j) = 1024, one chain;
    //      A-operands from registers, B from zt LDS; 4 chains over kk&3.
    f32x4 acc0 = {0.f,0.f,0.f,0.f}, acc1 = {0.f,0.f,0.f,0.f};
    f32x4 acc2 = {0.f,0.f,0.f,0.f}, acc3 = {0.f,0.f,0.f,0.f};
    #pragma unroll
    for (int kk = 0; kk < 32; ++kk) {
        const int e = kk >> 1, jh = kk & 1;
        f16x8 zb = *(const f16x8*)&zt[((e << 4) + ln) * LSTR + jh * 32 + q * 8];
        switch (kk & 3) {
            case 0: acc0 = __builtin_amdgcn_mfma_f32_16x16x32_f16(ha[kk], zb, acc0, 0, 0, 0); break;
            case 1: acc1 = __builtin_amdgcn_mfma_f32_16x16x32_f16(ha[kk], zb, acc1, 0, 0, 0); break;
            case 2: acc2 = __builtin_amdgcn_mfma_f32_16x16x32_f16(ha[kk], zb, acc2, 0, 0, 0); break;
            default: acc3 = __builtin_amdgcn_mfma_f32_16x16x32_f16(ha[kk], zb, acc3, 0, 0, 0); break;
        }
    }
    // node_lin: acc += xn @ nw (B-frags prefetched at top)
    acc0 = __builtin_amdgcn_mfma_f32_16x16x32_f16(xa0, nb0, acc0, 0, 0, 0);
    acc1 = __builtin_amdgcn_mfma_f32_16x16x32_f16(xa1, nb1, acc1, 0, 0, 0);

    // epilogue: merge chains, + t2[o] (nb folded in), exact GELU, store per mode
    {
        const int o = (quar << 4) + ln;
        if (bf) {
            u16* ob = (u16*)out + (bt << 12);
            #pragma unroll
            for (int r = 0; r < 4; ++r) {
                int i = wave * 16 + q * 4 + r;
                float v = acc0[r] + acc1[r] + acc2[r] + acc3[r] + add;
                ob[(i << 6) + o] = f2bf(gelu_exact(v));
            }
        } else {
            float* ob = (float*)out + (bt << 12);
            #pragma unroll
            for (int r = 0; r < 4; ++r) {
                int i = wave * 16 + q * 4 + r;
                float v = acc0[r] + acc1[r] + acc2[r] + acc3[r] + add;
                ob[(i << 6) + o] = gelu_exact(v);
            }
        }
    }
}

extern "C" void kernel_launch(void* const* d_in, const int* in_sizes, int n_in,
                              void* d_out, int out_size, void* d_ws, size_t ws_size,
                              hipStream_t stream) {
    const void* x   = d_in[0];
    const void* adj = d_in[1];
    const void* ew1 = d_in[2];
    const void* eb1 = d_in[3];
    const void* ew2 = d_in[4];
    const void* eb2 = d_in[5];
    const void* nw  = d_in[6];
    const void* nb  = d_in[7];
    const void* gw  = d_in[8];
    const void* gb  = d_in[9];
    const void* gms = d_in[10];

    f16* ws = (f16*)d_ws;   // ~944 KB used, see layout comment

    precomp<<<512, 256, 0, stream>>>(x, adj, ew1, eb1, ew2, eb2, nw, nb,
                                     gw, gb, gms, ws);
    fused_main<<<256, 256, 0, stream>>>(ws, d_out);
}